// Round 1
// baseline (366.733 us; speedup 1.0000x reference)
//
#include <hip/hip_runtime.h>
#include <stdint.h>

#define B_  4
#define T_  2048
#define D_  1024
#define H_  16
#define HD_ 64

typedef __bf16 bf16_t;
typedef __bf16 bf16x8 __attribute__((ext_vector_type(8)));
typedef float  f32x4  __attribute__((ext_vector_type(4)));

__device__ __forceinline__ uint16_t f2bf(float f) {
  uint32_t x = __float_as_uint(f);
  uint32_t r = (x + 0x7fffu + ((x >> 16) & 1u)) >> 16;
  return (uint16_t)r;
}

__device__ __forceinline__ uint32_t pack2(float a, float b) {
  return (uint32_t)f2bf(a) | ((uint32_t)f2bf(b) << 16);
}

// async 16B global->LDS; lds dst is wave-uniform base (+lane*16 by HW)
__device__ __forceinline__ void gll16(const void* g, void* l) {
  __builtin_amdgcn_global_load_lds(
      (const __attribute__((address_space(1))) void*)g,
      (__attribute__((address_space(3))) void*)l, 16, 0, 0);
}

// ---------------- fp32 -> bf16 conversion ----------------
__global__ __launch_bounds__(256) void cvt_bf16(const float* __restrict__ in,
                                                uint16_t* __restrict__ out, int n) {
  int i = (blockIdx.x * 256 + threadIdx.x) * 8;
  if (i >= n) return;
  float4 a = *(const float4*)(in + i);
  float4 b = *(const float4*)(in + i + 4);
  uint4 u;
  u.x = pack2(a.x, a.y);
  u.y = pack2(a.z, a.w);
  u.z = pack2(b.x, b.y);
  u.w = pack2(b.z, b.w);
  *(uint4*)(out + i) = u;
}

// ---------------- GEMM: C = A[M,K] @ W[N,K]^T ----------------
// MODE 0: Q -> bf16 [B,H,T,64], scaled
// MODE 1: K -> bf16 [B,H,T,64]
// MODE 2: V -> bf16 [B,H,64,T]  (transposed per head)
// MODE 3: O -> fp32 [M, D_]
template <int MODE>
__global__ __launch_bounds__(256, 2)
void gemm_bt(const uint16_t* __restrict__ A, const uint16_t* __restrict__ W,
             void* __restrict__ Out, int K, float scale) {
  __shared__ __align__(16) uint16_t As[128 * 64];
  __shared__ __align__(16) uint16_t Bs[128 * 64];
  const int tid = threadIdx.x;
  const int wid = tid >> 6, lane = tid & 63;
  const int fr = lane & 15, fq = lane >> 4;
  const int wr = wid >> 1, wc = wid & 1;
  const int m0 = blockIdx.x * 128, n0 = blockIdx.y * 128;
  const int srow = lane >> 3, c8 = lane & 7;

  f32x4 acc[4][4];
#pragma unroll
  for (int i = 0; i < 4; ++i)
#pragma unroll
    for (int j = 0; j < 4; ++j) acc[i][j] = (f32x4){0.f, 0.f, 0.f, 0.f};

  for (int k0 = 0; k0 < K; k0 += 64) {
#pragma unroll
    for (int c = 0; c < 4; ++c) {
      int slot = wid * 4 + c;
      int row = slot * 8 + srow;
      int sw = (c8 ^ (row & 7)) << 3;  // swizzled element offset within 64-elem row
      gll16(A + (size_t)(m0 + row) * K + k0 + sw, &As[slot * 512]);
      gll16(W + (size_t)(n0 + row) * K + k0 + sw, &Bs[slot * 512]);
    }
    __syncthreads();
#pragma unroll
    for (int ks = 0; ks < 2; ++ks) {
      bf16x8 af[4], bfr[4];
#pragma unroll
      for (int mf = 0; mf < 4; ++mf) {
        int r = wr * 64 + mf * 16 + fr;
        int ch = (fq + ks * 4) ^ (r & 7);
        af[mf] = *(const bf16x8*)&As[r * 64 + ch * 8];
      }
#pragma unroll
      for (int nf = 0; nf < 4; ++nf) {
        int r = wc * 64 + nf * 16 + fr;
        int ch = (fq + ks * 4) ^ (r & 7);
        bfr[nf] = *(const bf16x8*)&Bs[r * 64 + ch * 8];
      }
#pragma unroll
      for (int mf = 0; mf < 4; ++mf)
#pragma unroll
        for (int nf = 0; nf < 4; ++nf)
          acc[mf][nf] = __builtin_amdgcn_mfma_f32_16x16x32_bf16(af[mf], bfr[nf],
                                                                acc[mf][nf], 0, 0, 0);
    }
    __syncthreads();
  }

  // epilogue
#pragma unroll
  for (int mf = 0; mf < 4; ++mf) {
#pragma unroll
    for (int nf = 0; nf < 4; ++nf) {
      if (MODE == 2) {
        int m = m0 + wr * 64 + mf * 16 + fq * 4;  // r=0 base; t consecutive over r
        int n = n0 + wc * 64 + nf * 16 + fr;
        int b = m >> 11, t = m & (T_ - 1);
        int h = n >> 6, hd = n & 63;
        uint2 pk;
        pk.x = pack2(acc[mf][nf][0], acc[mf][nf][1]);
        pk.y = pack2(acc[mf][nf][2], acc[mf][nf][3]);
        uint16_t* dst = (uint16_t*)Out +
                        ((((size_t)b * H_ + h) * HD_ + hd) * T_ + t);
        *(uint2*)dst = pk;
      } else {
#pragma unroll
        for (int r = 0; r < 4; ++r) {
          int m = m0 + wr * 64 + mf * 16 + fq * 4 + r;
          int n = n0 + wc * 64 + nf * 16 + fr;
          float v = acc[mf][nf][r] * scale;
          if (MODE == 3) {
            ((float*)Out)[(size_t)m * D_ + n] = v;
          } else {
            int b = m >> 11, t = m & (T_ - 1);
            int h = n >> 6, hd = n & 63;
            ((uint16_t*)Out)[((((size_t)b * H_ + h) * T_ + t) << 6) + hd] = f2bf(v);
          }
        }
      }
    }
  }
}

// ---------------- flash attention (causal) ----------------
// Qh,Kh: [B,H,T,64] bf16 (Q pre-scaled). Vt: [B,H,64,T] bf16.
// O: bf16 [B,T,D] (heads concatenated).
__global__ __launch_bounds__(256, 2)
void attn_fwd(const uint16_t* __restrict__ Qh, const uint16_t* __restrict__ Kh,
              const uint16_t* __restrict__ Vt, uint16_t* __restrict__ O) {
  __shared__ __align__(16) uint16_t Klds[64 * 64];
  __shared__ __align__(16) uint16_t Vlds[64 * 64];
  __shared__ __align__(16) uint16_t Plds[4][16 * 64];

  const int tid = threadIdx.x, wid = tid >> 6, lane = tid & 63;
  const int fr = lane & 15, fq = lane >> 4;
  const int qt = blockIdx.x, bh = blockIdx.y;
  const size_t hoff = (size_t)bh * T_ * HD_;
  const uint16_t* Qb = Qh + hoff;
  const uint16_t* Kb = Kh + hoff;
  const uint16_t* Vb = Vt + hoff;
  const int srow = lane >> 3, c8 = lane & 7;

  // Q fragments held in registers for the whole block
  bf16x8 qa[2];
  {
    int qrow = qt * 64 + wid * 16 + fr;
    qa[0] = *(const bf16x8*)&Qb[(size_t)qrow * 64 + fq * 8];
    qa[1] = *(const bf16x8*)&Qb[(size_t)qrow * 64 + fq * 8 + 32];
  }

  float mrow[4], lrow[4];
  f32x4 acc[4];
#pragma unroll
  for (int r = 0; r < 4; ++r) { mrow[r] = -1e30f; lrow[r] = 0.f; }
#pragma unroll
  for (int nf = 0; nf < 4; ++nf) acc[nf] = (f32x4){0.f, 0.f, 0.f, 0.f};

  for (int kvt = 0; kvt <= qt; ++kvt) {
#pragma unroll
    for (int c = 0; c < 2; ++c) {
      int slot = wid * 2 + c;
      int row = slot * 8 + srow;
      int sw = (c8 ^ (row & 7)) << 3;
      gll16(Kb + (size_t)(kvt * 64 + row) * 64 + sw, &Klds[slot * 512]);
      gll16(Vb + (size_t)row * T_ + kvt * 64 + sw, &Vlds[slot * 512]);
    }
    __syncthreads();

    // S = Q @ K^T  (16 q-rows per wave x 64 kv)
    f32x4 s[4];
#pragma unroll
    for (int nf = 0; nf < 4; ++nf) {
      s[nf] = (f32x4){0.f, 0.f, 0.f, 0.f};
#pragma unroll
      for (int ks = 0; ks < 2; ++ks) {
        int r = nf * 16 + fr;
        int ch = (fq + ks * 4) ^ (r & 7);
        bf16x8 kb = *(const bf16x8*)&Klds[r * 64 + ch * 8];
        s[nf] = __builtin_amdgcn_mfma_f32_16x16x32_bf16(qa[ks], kb, s[nf], 0, 0, 0);
      }
    }

    // causal mask (diagonal tile only)
    if (kvt == qt) {
#pragma unroll
      for (int nf = 0; nf < 4; ++nf)
#pragma unroll
        for (int r = 0; r < 4; ++r)
          if (nf * 16 + fr > wid * 16 + fq * 4 + r) s[nf][r] = -1e30f;
    }

    // online softmax
    float pm[4], sf[4], rs[4], p[4][4];
#pragma unroll
    for (int r = 0; r < 4; ++r)
      pm[r] = fmaxf(fmaxf(s[0][r], s[1][r]), fmaxf(s[2][r], s[3][r]));
#pragma unroll
    for (int off = 1; off < 16; off <<= 1)
#pragma unroll
      for (int r = 0; r < 4; ++r) pm[r] = fmaxf(pm[r], __shfl_xor(pm[r], off));
#pragma unroll
    for (int r = 0; r < 4; ++r) {
      float mn = fmaxf(mrow[r], pm[r]);
      sf[r] = __expf(mrow[r] - mn);
      mrow[r] = mn;
    }
#pragma unroll
    for (int nf = 0; nf < 4; ++nf)
#pragma unroll
      for (int r = 0; r < 4; ++r) p[nf][r] = __expf(s[nf][r] - mrow[r]);
#pragma unroll
    for (int r = 0; r < 4; ++r) rs[r] = (p[0][r] + p[1][r]) + (p[2][r] + p[3][r]);
#pragma unroll
    for (int off = 1; off < 16; off <<= 1)
#pragma unroll
      for (int r = 0; r < 4; ++r) rs[r] += __shfl_xor(rs[r], off);
#pragma unroll
    for (int r = 0; r < 4; ++r) lrow[r] = lrow[r] * sf[r] + rs[r];
#pragma unroll
    for (int nf = 0; nf < 4; ++nf)
#pragma unroll
      for (int r = 0; r < 4; ++r) acc[nf][r] *= sf[r];

    // P -> per-wave LDS (swizzled), then PV
#pragma unroll
    for (int nf = 0; nf < 4; ++nf)
#pragma unroll
      for (int r = 0; r < 4; ++r) {
        int row = fq * 4 + r, col = nf * 16 + fr;
        int sc = (col >> 3) ^ (row & 7);
        Plds[wid][row * 64 + sc * 8 + (col & 7)] = f2bf(p[nf][r]);
      }
    asm volatile("s_waitcnt lgkmcnt(0)" ::: "memory");

#pragma unroll
    for (int ks = 0; ks < 2; ++ks) {
      int pch = (fq + ks * 4) ^ (fr & 7);
      bf16x8 pa = *(const bf16x8*)&Plds[wid][fr * 64 + pch * 8];
#pragma unroll
      for (int nf = 0; nf < 4; ++nf) {
        int vrow = nf * 16 + fr;
        int vch = (fq + ks * 4) ^ (vrow & 7);
        bf16x8 vb = *(const bf16x8*)&Vlds[vrow * 64 + vch * 8];
        acc[nf] = __builtin_amdgcn_mfma_f32_16x16x32_bf16(pa, vb, acc[nf], 0, 0, 0);
      }
    }
    __syncthreads();
  }

  // epilogue: normalize, stage in LDS, coalesced store
#pragma unroll
  for (int nf = 0; nf < 4; ++nf) {
#pragma unroll
    for (int r = 0; r < 4; ++r) {
      int row = wid * 16 + fq * 4 + r, col = nf * 16 + fr;
      Klds[row * 64 + col] = f2bf(acc[nf][r] / lrow[r]);
    }
  }
  __syncthreads();
  {
    int row = tid >> 2, cs = tid & 3;
    int b = bh >> 4, h = bh & 15;
    size_t g = (size_t)(b * T_ + qt * 64 + row) * D_ + h * 64 + cs * 16;
    const uint4* src = (const uint4*)&Klds[row * 64 + cs * 16];
    *(uint4*)&O[g] = src[0];
    *(uint4*)&O[g + 8] = src[1];
  }
}

// ---------------- launcher ----------------
extern "C" void kernel_launch(void* const* d_in, const int* in_sizes, int n_in,
                              void* d_out, int out_size, void* d_ws, size_t ws_size,
                              hipStream_t stream) {
  (void)in_sizes; (void)n_in; (void)out_size; (void)ws_size;
  const float* q  = (const float*)d_in[0];
  const float* k  = (const float*)d_in[1];
  const float* v  = (const float*)d_in[2];
  // d_in[3] = mask (causal; structure hardcoded)
  const float* Wq = (const float*)d_in[4];
  const float* Wk = (const float*)d_in[5];
  const float* Wv = (const float*)d_in[6];
  const float* Wo = (const float*)d_in[7];

  uint8_t* ws = (uint8_t*)d_ws;
  const size_t MB = 1u << 20;
  uint16_t* WQB = (uint16_t*)(ws + 0 * MB);
  uint16_t* WKB = (uint16_t*)(ws + 2 * MB);
  uint16_t* WVB = (uint16_t*)(ws + 4 * MB);
  uint16_t* WOB = (uint16_t*)(ws + 6 * MB);
  uint16_t* XQ  = (uint16_t*)(ws + 8 * MB);
  uint16_t* XK  = (uint16_t*)(ws + 24 * MB);
  uint16_t* XV  = (uint16_t*)(ws + 40 * MB);
  uint16_t* QH  = (uint16_t*)(ws + 56 * MB);
  uint16_t* KH  = (uint16_t*)(ws + 72 * MB);
  uint16_t* VT  = (uint16_t*)(ws + 88 * MB);
  uint16_t* AC  = (uint16_t*)(ws + 8 * MB);  // alias XQ (dead after Q proj)

  const int nBig = B_ * T_ * D_;   // 8388608
  const int nW   = D_ * D_;        // 1048576
  cvt_bf16<<<nBig / 2048, 256, 0, stream>>>(q, XQ, nBig);
  cvt_bf16<<<nBig / 2048, 256, 0, stream>>>(k, XK, nBig);
  cvt_bf16<<<nBig / 2048, 256, 0, stream>>>(v, XV, nBig);
  cvt_bf16<<<nW / 2048, 256, 0, stream>>>(Wq, WQB, nW);
  cvt_bf16<<<nW / 2048, 256, 0, stream>>>(Wk, WKB, nW);
  cvt_bf16<<<nW / 2048, 256, 0, stream>>>(Wv, WVB, nW);
  cvt_bf16<<<nW / 2048, 256, 0, stream>>>(Wo, WOB, nW);

  dim3 ggrid(B_ * T_ / 128, D_ / 128);
  const float qscale = 0.125f;  // HD^-0.5, exact in bf16
  gemm_bt<0><<<ggrid, 256, 0, stream>>>(XQ, WQB, QH, D_, qscale);
  gemm_bt<1><<<ggrid, 256, 0, stream>>>(XK, WKB, KH, D_, 1.0f);
  gemm_bt<2><<<ggrid, 256, 0, stream>>>(XV, WVB, VT, D_, 1.0f);

  attn_fwd<<<dim3(T_ / 64, B_ * H_), 256, 0, stream>>>(QH, KH, VT, AC);

  gemm_bt<3><<<ggrid, 256, 0, stream>>>(AC, WOB, d_out, D_, 1.0f);
}

// Round 2
// 249.027 us; speedup vs baseline: 1.4727x; 1.4727x over previous
//
#include <hip/hip_runtime.h>
#include <stdint.h>

#define B_  4
#define T_  2048
#define D_  1024
#define H_  16
#define HD_ 64

typedef __bf16 bf16_t;
typedef __bf16 bf16x8 __attribute__((ext_vector_type(8)));
typedef float  f32x4  __attribute__((ext_vector_type(4)));

__device__ __forceinline__ uint16_t f2bf(float f) {
  uint32_t x = __float_as_uint(f);
  uint32_t r = (x + 0x7fffu + ((x >> 16) & 1u)) >> 16;
  return (uint16_t)r;
}

__device__ __forceinline__ uint32_t pack2(float a, float b) {
  return (uint32_t)f2bf(a) | ((uint32_t)f2bf(b) << 16);
}

// async 16B global->LDS; lds dst is wave-uniform base (+lane*16 by HW)
__device__ __forceinline__ void gll16(const void* g, void* l) {
  __builtin_amdgcn_global_load_lds(
      (const __attribute__((address_space(1))) void*)g,
      (__attribute__((address_space(3))) void*)l, 16, 0, 0);
}

// ---------------- fp32 -> bf16 conversion ----------------
__global__ __launch_bounds__(256) void cvt_bf16(const float* __restrict__ in,
                                                uint16_t* __restrict__ out, int n) {
  int i = (blockIdx.x * 256 + threadIdx.x) * 8;
  if (i >= n) return;
  float4 a = *(const float4*)(in + i);
  float4 b = *(const float4*)(in + i + 4);
  uint4 u;
  u.x = pack2(a.x, a.y);
  u.y = pack2(a.z, a.w);
  u.z = pack2(b.x, b.y);
  u.w = pack2(b.z, b.w);
  *(uint4*)(out + i) = u;
}

// ---------------- GEMM: C = A[M,K] @ W[N,K]^T ----------------
// MODE 0: Q -> bf16 [B,H,T,64], scaled
// MODE 1: K -> bf16 [B,H,T,64]
// MODE 2: V -> bf16 [B,H,64,T]  (transposed per head)
// MODE 3: O -> fp32 [M, D_]
template <int MODE>
__global__ __launch_bounds__(256, 2)
void gemm_bt(const uint16_t* __restrict__ A, const uint16_t* __restrict__ W,
             void* __restrict__ Out, int K, float scale) {
  __shared__ __align__(16) uint16_t As[128 * 64];
  __shared__ __align__(16) uint16_t Bs[128 * 64];
  const int tid = threadIdx.x;
  const int wid = tid >> 6, lane = tid & 63;
  const int fr = lane & 15, fq = lane >> 4;
  const int wr = wid >> 1, wc = wid & 1;
  const int m0 = blockIdx.x * 128, n0 = blockIdx.y * 128;
  const int srow = lane >> 3, c8 = lane & 7;

  f32x4 acc[4][4];
#pragma unroll
  for (int i = 0; i < 4; ++i)
#pragma unroll
    for (int j = 0; j < 4; ++j) acc[i][j] = (f32x4){0.f, 0.f, 0.f, 0.f};

  for (int k0 = 0; k0 < K; k0 += 64) {
#pragma unroll
    for (int c = 0; c < 4; ++c) {
      int slot = wid * 4 + c;
      int row = slot * 8 + srow;
      int sw = (c8 ^ (row & 7)) << 3;  // swizzled element offset within 64-elem row
      gll16(A + (size_t)(m0 + row) * K + k0 + sw, &As[slot * 512]);
      gll16(W + (size_t)(n0 + row) * K + k0 + sw, &Bs[slot * 512]);
    }
    __syncthreads();
#pragma unroll
    for (int ks = 0; ks < 2; ++ks) {
      bf16x8 af[4], bfr[4];
#pragma unroll
      for (int mf = 0; mf < 4; ++mf) {
        int r = wr * 64 + mf * 16 + fr;
        int ch = (fq + ks * 4) ^ (r & 7);
        af[mf] = *(const bf16x8*)&As[r * 64 + ch * 8];
      }
#pragma unroll
      for (int nf = 0; nf < 4; ++nf) {
        int r = wc * 64 + nf * 16 + fr;
        int ch = (fq + ks * 4) ^ (r & 7);
        bfr[nf] = *(const bf16x8*)&Bs[r * 64 + ch * 8];
      }
#pragma unroll
      for (int mf = 0; mf < 4; ++mf)
#pragma unroll
        for (int nf = 0; nf < 4; ++nf)
          acc[mf][nf] = __builtin_amdgcn_mfma_f32_16x16x32_bf16(af[mf], bfr[nf],
                                                                acc[mf][nf], 0, 0, 0);
    }
    __syncthreads();
  }

  // epilogue
#pragma unroll
  for (int mf = 0; mf < 4; ++mf) {
#pragma unroll
    for (int nf = 0; nf < 4; ++nf) {
      if (MODE == 2) {
        int m = m0 + wr * 64 + mf * 16 + fq * 4;  // r=0 base; t consecutive over r
        int n = n0 + wc * 64 + nf * 16 + fr;
        int b = m >> 11, t = m & (T_ - 1);
        int h = n >> 6, hd = n & 63;
        uint2 pk;
        pk.x = pack2(acc[mf][nf][0], acc[mf][nf][1]);
        pk.y = pack2(acc[mf][nf][2], acc[mf][nf][3]);
        uint16_t* dst = (uint16_t*)Out +
                        ((((size_t)b * H_ + h) * HD_ + hd) * T_ + t);
        *(uint2*)dst = pk;
      } else {
#pragma unroll
        for (int r = 0; r < 4; ++r) {
          int m = m0 + wr * 64 + mf * 16 + fq * 4 + r;
          int n = n0 + wc * 64 + nf * 16 + fr;
          float v = acc[mf][nf][r] * scale;
          if (MODE == 3) {
            ((float*)Out)[(size_t)m * D_ + n] = v;
          } else {
            int b = m >> 11, t = m & (T_ - 1);
            int h = n >> 6, hd = n & 63;
            ((uint16_t*)Out)[((((size_t)b * H_ + h) * T_ + t) << 6) + hd] = f2bf(v);
          }
        }
      }
    }
  }
}

// ---------------- flash attention (causal), QBLK=128, double-buffered ----------------
// Qh,Kh: [B,H,T,64] bf16 (Q pre-scaled). Vt: [B,H,64,T] bf16.
// O: bf16 [B,T,D] (heads concatenated).
__global__ __launch_bounds__(256, 3)
void attn_fwd(const uint16_t* __restrict__ Qh, const uint16_t* __restrict__ Kh,
              const uint16_t* __restrict__ Vt, uint16_t* __restrict__ O) {
  __shared__ __align__(16) uint16_t Kb[2][64 * 64];   // 16 KB
  __shared__ __align__(16) uint16_t Vb[2][64 * 64];   // 16 KB
  __shared__ __align__(16) uint16_t Pl[4][32 * 64];   // 16 KB (per-wave P)

  const int tid = threadIdx.x, wid = tid >> 6, lane = tid & 63;
  const int fr = lane & 15, fq = lane >> 4;
  const int bid = blockIdx.x;
  const int qt = (T_ / 128 - 1) - (bid >> 6);  // longest blocks first
  const int bh = bid & 63;
  const int q0 = qt * 128;
  const size_t hoff = (size_t)bh * T_ * HD_;
  const uint16_t* Qp = Qh + hoff;
  const uint16_t* Kp = Kh + hoff;
  const uint16_t* Vp = Vt + hoff;
  const int srow = lane >> 3, c8 = lane & 7;
  const int wq0 = q0 + wid * 32;  // this wave's first q row

  // Q fragments in registers for the whole block: 2 m-frags x 2 k-slices
  bf16x8 qa[2][2];
#pragma unroll
  for (int m = 0; m < 2; ++m) {
    int qrow = wq0 + m * 16 + fr;
    qa[m][0] = *(const bf16x8*)&Qp[(size_t)qrow * 64 + fq * 8];
    qa[m][1] = *(const bf16x8*)&Qp[(size_t)qrow * 64 + fq * 8 + 32];
  }

  float mrow[2][4], lrow[2][4];
  f32x4 acc[2][4];
#pragma unroll
  for (int m = 0; m < 2; ++m)
#pragma unroll
    for (int r = 0; r < 4; ++r) { mrow[m][r] = -1e30f; lrow[m][r] = 0.f; }
#pragma unroll
  for (int m = 0; m < 2; ++m)
#pragma unroll
    for (int nf = 0; nf < 4; ++nf) acc[m][nf] = (f32x4){0.f, 0.f, 0.f, 0.f};

  const int ntiles = 2 * qt + 2;

#define STAGE(buf, t)                                                       \
  do {                                                                      \
    _Pragma("unroll")                                                       \
    for (int c = 0; c < 2; ++c) {                                           \
      int slot = wid * 2 + c;                                               \
      int row = slot * 8 + srow;                                            \
      int sw = (c8 ^ (row & 7)) << 3;                                       \
      gll16(Kp + (size_t)((t) * 64 + row) * 64 + sw, &Kb[buf][slot * 512]); \
      gll16(Vp + (size_t)row * T_ + (t) * 64 + sw, &Vb[buf][slot * 512]);   \
    }                                                                       \
  } while (0)

  STAGE(0, 0);
  asm volatile("s_waitcnt vmcnt(0)" ::: "memory");
  __builtin_amdgcn_s_barrier();

  for (int it = 0; it < ntiles; ++it) {
    const int cur = it & 1;
    if (it + 1 < ntiles) STAGE(cur ^ 1, it + 1);  // prefetch next tile

    // wave is active unless the whole tile is above the causal diagonal
    if (it * 64 <= wq0 + 31) {
      // S = Q @ K^T
      f32x4 s[2][4];
#pragma unroll
      for (int m = 0; m < 2; ++m)
#pragma unroll
        for (int nf = 0; nf < 4; ++nf) s[m][nf] = (f32x4){0.f, 0.f, 0.f, 0.f};
#pragma unroll
      for (int ks = 0; ks < 2; ++ks) {
#pragma unroll
        for (int nf = 0; nf < 4; ++nf) {
          int r = nf * 16 + fr;
          int ch = (fq + ks * 4) ^ (r & 7);
          bf16x8 kb = *(const bf16x8*)&Kb[cur][r * 64 + ch * 8];
          s[0][nf] = __builtin_amdgcn_mfma_f32_16x16x32_bf16(qa[0][ks], kb, s[0][nf], 0, 0, 0);
          s[1][nf] = __builtin_amdgcn_mfma_f32_16x16x32_bf16(qa[1][ks], kb, s[1][nf], 0, 0, 0);
        }
      }

      // causal mask (only tiles straddling the diagonal)
      if (it * 64 + 63 > wq0) {
#pragma unroll
        for (int m = 0; m < 2; ++m)
#pragma unroll
          for (int nf = 0; nf < 4; ++nf)
#pragma unroll
            for (int r = 0; r < 4; ++r)
              if (it * 64 + nf * 16 + fr > wq0 + m * 16 + fq * 4 + r)
                s[m][nf][r] = -1e30f;
      }

      // online softmax (q-row = (m, fq, r); kv spread over nf in-lane and fr cross-lane)
      float sf[2][4];
#pragma unroll
      for (int m = 0; m < 2; ++m) {
        float pm[4];
#pragma unroll
        for (int r = 0; r < 4; ++r)
          pm[r] = fmaxf(fmaxf(s[m][0][r], s[m][1][r]), fmaxf(s[m][2][r], s[m][3][r]));
#pragma unroll
        for (int off = 1; off < 16; off <<= 1)
#pragma unroll
          for (int r = 0; r < 4; ++r) pm[r] = fmaxf(pm[r], __shfl_xor(pm[r], off));
#pragma unroll
        for (int r = 0; r < 4; ++r) {
          float mn = fmaxf(mrow[m][r], pm[r]);
          sf[m][r] = __expf(mrow[m][r] - mn);
          mrow[m][r] = mn;
        }
      }
      float rs[2][4];
#pragma unroll
      for (int m = 0; m < 2; ++m)
#pragma unroll
        for (int r = 0; r < 4; ++r) rs[m][r] = 0.f;
#pragma unroll
      for (int m = 0; m < 2; ++m)
#pragma unroll
        for (int nf = 0; nf < 4; ++nf)
#pragma unroll
          for (int r = 0; r < 4; ++r) {
            float p = __expf(s[m][nf][r] - mrow[m][r]);
            rs[m][r] += p;
            int row = m * 16 + fq * 4 + r, col = nf * 16 + fr;
            int sc = (col >> 3) ^ (row & 7);
            Pl[wid][row * 64 + sc * 8 + (col & 7)] = f2bf(p);
          }
#pragma unroll
      for (int off = 1; off < 16; off <<= 1)
#pragma unroll
        for (int m = 0; m < 2; ++m)
#pragma unroll
          for (int r = 0; r < 4; ++r) rs[m][r] += __shfl_xor(rs[m][r], off);
#pragma unroll
      for (int m = 0; m < 2; ++m)
#pragma unroll
        for (int r = 0; r < 4; ++r) lrow[m][r] = lrow[m][r] * sf[m][r] + rs[m][r];
#pragma unroll
      for (int m = 0; m < 2; ++m)
#pragma unroll
        for (int nf = 0; nf < 4; ++nf)
#pragma unroll
          for (int r = 0; r < 4; ++r) acc[m][nf][r] *= sf[m][r];

      asm volatile("s_waitcnt lgkmcnt(0)" ::: "memory");  // P writes visible to own wave

      // PV: acc += P @ V^T-tile
#pragma unroll
      for (int ks = 0; ks < 2; ++ks) {
        bf16x8 pa[2];
#pragma unroll
        for (int m = 0; m < 2; ++m) {
          int row = m * 16 + fr;
          int pch = (fq + ks * 4) ^ (row & 7);
          pa[m] = *(const bf16x8*)&Pl[wid][row * 64 + pch * 8];
        }
#pragma unroll
        for (int nf = 0; nf < 4; ++nf) {
          int vrow = nf * 16 + fr;
          int vch = (fq + ks * 4) ^ (vrow & 7);
          bf16x8 vb = *(const bf16x8*)&Vb[cur][vrow * 64 + vch * 8];
          acc[0][nf] = __builtin_amdgcn_mfma_f32_16x16x32_bf16(pa[0], vb, acc[0][nf], 0, 0, 0);
          acc[1][nf] = __builtin_amdgcn_mfma_f32_16x16x32_bf16(pa[1], vb, acc[1][nf], 0, 0, 0);
        }
      }
    }

    asm volatile("s_waitcnt vmcnt(0)" ::: "memory");  // next tile's stage landed
    __builtin_amdgcn_s_barrier();
  }
#undef STAGE

  // epilogue: normalize, stage 128x64 tile in LDS (reuse Kb), coalesced store
  uint16_t* ost = &Kb[0][0];
#pragma unroll
  for (int m = 0; m < 2; ++m)
#pragma unroll
    for (int nf = 0; nf < 4; ++nf)
#pragma unroll
      for (int r = 0; r < 4; ++r) {
        int row = wid * 32 + m * 16 + fq * 4 + r, col = nf * 16 + fr;
        ost[row * 64 + col] = f2bf(acc[m][nf][r] / lrow[m][r]);
      }
  __syncthreads();
  {
    int row = tid >> 1, c0 = (tid & 1) * 32;
    int b = bh >> 4, h = bh & 15;
    size_t g = (size_t)(b * T_ + q0 + row) * D_ + h * 64 + c0;
    const uint4* src = (const uint4*)&ost[row * 64 + c0];
    uint4* dst = (uint4*)&O[g];
#pragma unroll
    for (int j = 0; j < 4; ++j) dst[j] = src[j];
  }
}

// ---------------- launcher ----------------
extern "C" void kernel_launch(void* const* d_in, const int* in_sizes, int n_in,
                              void* d_out, int out_size, void* d_ws, size_t ws_size,
                              hipStream_t stream) {
  (void)in_sizes; (void)n_in; (void)out_size; (void)ws_size;
  const float* q  = (const float*)d_in[0];
  const float* k  = (const float*)d_in[1];
  const float* v  = (const float*)d_in[2];
  // d_in[3] = mask (causal; structure hardcoded)
  const float* Wq = (const float*)d_in[4];
  const float* Wk = (const float*)d_in[5];
  const float* Wv = (const float*)d_in[6];
  const float* Wo = (const float*)d_in[7];

  uint8_t* ws = (uint8_t*)d_ws;
  const size_t MB = 1u << 20;
  uint16_t* WQB = (uint16_t*)(ws + 0 * MB);
  uint16_t* WKB = (uint16_t*)(ws + 2 * MB);
  uint16_t* WVB = (uint16_t*)(ws + 4 * MB);
  uint16_t* WOB = (uint16_t*)(ws + 6 * MB);
  uint16_t* XQ  = (uint16_t*)(ws + 8 * MB);
  uint16_t* XK  = (uint16_t*)(ws + 24 * MB);
  uint16_t* XV  = (uint16_t*)(ws + 40 * MB);
  uint16_t* QH  = (uint16_t*)(ws + 56 * MB);
  uint16_t* KH  = (uint16_t*)(ws + 72 * MB);
  uint16_t* VT  = (uint16_t*)(ws + 88 * MB);
  uint16_t* AC  = (uint16_t*)(ws + 8 * MB);  // alias XQ (dead after Q proj)

  const int nBig = B_ * T_ * D_;   // 8388608
  const int nW   = D_ * D_;        // 1048576
  cvt_bf16<<<nBig / 2048, 256, 0, stream>>>(q, XQ, nBig);
  cvt_bf16<<<nBig / 2048, 256, 0, stream>>>(k, XK, nBig);
  cvt_bf16<<<nBig / 2048, 256, 0, stream>>>(v, XV, nBig);
  cvt_bf16<<<nW / 2048, 256, 0, stream>>>(Wq, WQB, nW);
  cvt_bf16<<<nW / 2048, 256, 0, stream>>>(Wk, WKB, nW);
  cvt_bf16<<<nW / 2048, 256, 0, stream>>>(Wv, WVB, nW);
  cvt_bf16<<<nW / 2048, 256, 0, stream>>>(Wo, WOB, nW);

  dim3 ggrid(B_ * T_ / 128, D_ / 128);
  const float qscale = 0.125f;  // HD^-0.5, exact in bf16
  gemm_bt<0><<<ggrid, 256, 0, stream>>>(XQ, WQB, QH, D_, qscale);
  gemm_bt<1><<<ggrid, 256, 0, stream>>>(XK, WKB, KH, D_, 1.0f);
  gemm_bt<2><<<ggrid, 256, 0, stream>>>(XV, WVB, VT, D_, 1.0f);

  attn_fwd<<<dim3(T_ / 128 * 64), 256, 0, stream>>>(QH, KH, VT, AC);

  gemm_bt<3><<<ggrid, 256, 0, stream>>>(AC, WOB, d_out, D_, 1.0f);
}

// Round 3
// 186.354 us; speedup vs baseline: 1.9679x; 1.3363x over previous
//
#include <hip/hip_runtime.h>
#include <stdint.h>

#define B_  4
#define T_  2048
#define D_  1024
#define H_  16
#define HD_ 64

typedef __bf16 bf16_t;
typedef __bf16 bf16x8 __attribute__((ext_vector_type(8)));
typedef float  f32x4  __attribute__((ext_vector_type(4)));
typedef float  f32x16 __attribute__((ext_vector_type(16)));

__device__ __forceinline__ uint16_t f2bf(float f) {
  uint32_t x = __float_as_uint(f);
  uint32_t r = (x + 0x7fffu + ((x >> 16) & 1u)) >> 16;
  return (uint16_t)r;
}

__device__ __forceinline__ uint32_t pack2(float a, float b) {
  return (uint32_t)f2bf(a) | ((uint32_t)f2bf(b) << 16);
}

// hardware 2^x
__device__ __forceinline__ float exp2a(float x) {
  float r;
  asm("v_exp_f32 %0, %1" : "=v"(r) : "v"(x));
  return r;
}

// v_cvt_pk_bf16_f32: dst.lo = bf16(a), dst.hi = bf16(b)
__device__ __forceinline__ uint32_t cvtpk(float a, float b) {
  uint32_t r;
  asm("v_cvt_pk_bf16_f32 %0, %1, %2" : "=v"(r) : "v"(a), "v"(b));
  return r;
}

// swap: a' = {a_lo, b_lo}, b' = {a_hi, b_hi}
__device__ __forceinline__ void plswap(uint32_t& a, uint32_t& b) {
  asm("v_permlane32_swap_b32 %0, %1" : "+v"(a), "+v"(b));
}

// async 16B global->LDS; lds dst is wave-uniform base (+lane*16 by HW)
__device__ __forceinline__ void gll16(const void* g, void* l) {
  __builtin_amdgcn_global_load_lds(
      (const __attribute__((address_space(1))) void*)g,
      (__attribute__((address_space(3))) void*)l, 16, 0, 0);
}

// ---------------- fp32 -> bf16 conversion ----------------
__global__ __launch_bounds__(256) void cvt_bf16(const float* __restrict__ in,
                                                uint16_t* __restrict__ out, int n) {
  int i = (blockIdx.x * 256 + threadIdx.x) * 8;
  if (i >= n) return;
  float4 a = *(const float4*)(in + i);
  float4 b = *(const float4*)(in + i + 4);
  uint4 u;
  u.x = pack2(a.x, a.y);
  u.y = pack2(a.z, a.w);
  u.z = pack2(b.x, b.y);
  u.w = pack2(b.z, b.w);
  *(uint4*)(out + i) = u;
}

// ---------------- GEMM: C = A[M,K] @ W[N,K]^T ----------------
// MODE 0: Q -> bf16 [B,H,T,64], scaled
// MODE 1: K -> bf16 [B,H,T,64]
// MODE 2: V -> bf16 [B,H,64,T]  (transposed per head)
// MODE 3: O -> fp32 [M, D_]
template <int MODE>
__global__ __launch_bounds__(256, 2)
void gemm_bt(const uint16_t* __restrict__ A, const uint16_t* __restrict__ W,
             void* __restrict__ Out, int K, float scale) {
  __shared__ __align__(16) uint16_t As[128 * 64];
  __shared__ __align__(16) uint16_t Bs[128 * 64];
  const int tid = threadIdx.x;
  const int wid = tid >> 6, lane = tid & 63;
  const int fr = lane & 15, fq = lane >> 4;
  const int wr = wid >> 1, wc = wid & 1;
  const int m0 = blockIdx.x * 128, n0 = blockIdx.y * 128;
  const int srow = lane >> 3, c8 = lane & 7;

  f32x4 acc[4][4];
#pragma unroll
  for (int i = 0; i < 4; ++i)
#pragma unroll
    for (int j = 0; j < 4; ++j) acc[i][j] = (f32x4){0.f, 0.f, 0.f, 0.f};

  for (int k0 = 0; k0 < K; k0 += 64) {
#pragma unroll
    for (int c = 0; c < 4; ++c) {
      int slot = wid * 4 + c;
      int row = slot * 8 + srow;
      int sw = (c8 ^ (row & 7)) << 3;  // swizzled element offset within 64-elem row
      gll16(A + (size_t)(m0 + row) * K + k0 + sw, &As[slot * 512]);
      gll16(W + (size_t)(n0 + row) * K + k0 + sw, &Bs[slot * 512]);
    }
    __syncthreads();
#pragma unroll
    for (int ks = 0; ks < 2; ++ks) {
      bf16x8 af[4], bfr[4];
#pragma unroll
      for (int mf = 0; mf < 4; ++mf) {
        int r = wr * 64 + mf * 16 + fr;
        int ch = (fq + ks * 4) ^ (r & 7);
        af[mf] = *(const bf16x8*)&As[r * 64 + ch * 8];
      }
#pragma unroll
      for (int nf = 0; nf < 4; ++nf) {
        int r = wc * 64 + nf * 16 + fr;
        int ch = (fq + ks * 4) ^ (r & 7);
        bfr[nf] = *(const bf16x8*)&Bs[r * 64 + ch * 8];
      }
#pragma unroll
      for (int mf = 0; mf < 4; ++mf)
#pragma unroll
        for (int nf = 0; nf < 4; ++nf)
          acc[mf][nf] = __builtin_amdgcn_mfma_f32_16x16x32_bf16(af[mf], bfr[nf],
                                                                acc[mf][nf], 0, 0, 0);
    }
    __syncthreads();
  }

  // epilogue
#pragma unroll
  for (int mf = 0; mf < 4; ++mf) {
#pragma unroll
    for (int nf = 0; nf < 4; ++nf) {
      if (MODE == 2) {
        int m = m0 + wr * 64 + mf * 16 + fq * 4;  // r=0 base; t consecutive over r
        int n = n0 + wc * 64 + nf * 16 + fr;
        int b = m >> 11, t = m & (T_ - 1);
        int h = n >> 6, hd = n & 63;
        uint2 pk;
        pk.x = pack2(acc[mf][nf][0], acc[mf][nf][1]);
        pk.y = pack2(acc[mf][nf][2], acc[mf][nf][3]);
        uint16_t* dst = (uint16_t*)Out +
                        ((((size_t)b * H_ + h) * HD_ + hd) * T_ + t);
        *(uint2*)dst = pk;
      } else {
#pragma unroll
        for (int r = 0; r < 4; ++r) {
          int m = m0 + wr * 64 + mf * 16 + fq * 4 + r;
          int n = n0 + wc * 64 + nf * 16 + fr;
          float v = acc[mf][nf][r] * scale;
          if (MODE == 3) {
            ((float*)Out)[(size_t)m * D_ + n] = v;
          } else {
            int b = m >> 11, t = m & (T_ - 1);
            int h = n >> 6, hd = n & 63;
            ((uint16_t*)Out)[((((size_t)b * H_ + h) * T_ + t) << 6) + hd] = f2bf(v);
          }
        }
      }
    }
  }
}

// ---------------- flash attention (causal), 8 waves x 32 q, 32x32 swapped ----------------
// Qh,Kh: [B,H,T,64] bf16 (Q pre-scaled by 0.125*log2e -> exp2 domain). Vt: [B,H,64,T] bf16.
// O: bf16 [B,T,D] (heads concatenated).
__global__ __launch_bounds__(512)
void attn_fwd(const uint16_t* __restrict__ Qh, const uint16_t* __restrict__ Kh,
              const uint16_t* __restrict__ Vt, uint16_t* __restrict__ O) {
  // SB[0..1] = K double buffer, SB[2..3] = V double buffer; epilogue reuses all 32KB
  __shared__ __align__(16) uint16_t SB[4][64 * 64];

  const int tid = threadIdx.x, wid = tid >> 6, lane = tid & 63;
  const int ql = lane & 31, hi = lane >> 5;
  const int bid = blockIdx.x;
  const int qb = (T_ / 256 - 1) - (bid >> 6);  // longest blocks first
  const int bh = bid & 63;
  const int q0 = qb * 256;
  const int wq0 = q0 + wid * 32;  // this wave's first q row
  const size_t hoff = (size_t)bh * T_ * HD_;
  const uint16_t* Qp = Qh + hoff;
  const uint16_t* Kp = Kh + hoff;
  const uint16_t* Vp = Vt + hoff;

  // Q fragments (B-operand): lane owns q-row (wq0+ql); k = hd = ks*16 + hi*8 + j
  bf16x8 qf[4];
  {
    const uint16_t* qrow = Qp + (size_t)(wq0 + ql) * 64 + hi * 8;
#pragma unroll
    for (int ks = 0; ks < 4; ++ks) qf[ks] = *(const bf16x8*)(qrow + ks * 16);
  }

  float m = -1e30f, l = 0.f;
  f32x16 acc[2];  // O^T: row = hd = mo*32 + (r&3)+8*(r>>2)+4*hi, col = q = ql
#pragma unroll
  for (int mo = 0; mo < 2; ++mo)
#pragma unroll
    for (int r = 0; r < 16; ++r) acc[mo][r] = 0.f;

  const int ntiles = 4 * qb + 4;

#define STAGE(buf, t)                                                        \
  do {                                                                       \
    int row = wid * 8 + (lane >> 3);                                         \
    int sw = ((lane & 7) ^ (row & 7)) << 3;                                  \
    gll16(Kp + (size_t)((t) * 64 + row) * 64 + sw, &SB[buf][wid * 512]);     \
    gll16(Vp + (size_t)row * T_ + (t) * 64 + sw, &SB[2 + (buf)][wid * 512]); \
  } while (0)

  STAGE(0, 0);
  asm volatile("s_waitcnt vmcnt(0)" ::: "memory");
  __builtin_amdgcn_s_barrier();

  for (int it = 0; it < ntiles; ++it) {
    const int cur = it & 1;
    if (it + 1 < ntiles) STAGE(cur ^ 1, it + 1);  // prefetch next tile

    if (it * 64 <= wq0 + 31) {  // wave active unless whole tile above diagonal
      // S^T = K @ Q : col = q (lane-local), rows = kv
      f32x16 st[2];
#pragma unroll
      for (int mm = 0; mm < 2; ++mm)
#pragma unroll
        for (int r = 0; r < 16; ++r) st[mm][r] = 0.f;
#pragma unroll
      for (int ks = 0; ks < 4; ++ks) {
#pragma unroll
        for (int mm = 0; mm < 2; ++mm) {
          int row = mm * 32 + ql;
          int ch = (ks * 2 + hi) ^ (row & 7);
          bf16x8 kf = *(const bf16x8*)&SB[cur][row * 64 + ch * 8];
          st[mm] = __builtin_amdgcn_mfma_f32_32x32x16_bf16(kf, qf[ks], st[mm], 0, 0, 0);
        }
      }

      // causal mask (diagonal-straddling tiles only)
      if (it * 64 + 63 > wq0) {
        int qg = wq0 + ql;
#pragma unroll
        for (int mm = 0; mm < 2; ++mm)
#pragma unroll
          for (int r = 0; r < 16; ++r) {
            int kv = it * 64 + mm * 32 + (r & 3) + 8 * (r >> 2) + 4 * hi;
            if (kv > qg) st[mm][r] = -1e30f;
          }
      }

      // row max: 32 in-lane + pair lane
      float pm = st[0][0];
#pragma unroll
      for (int r = 1; r < 16; ++r) pm = fmaxf(pm, st[0][r]);
#pragma unroll
      for (int r = 0; r < 16; ++r) pm = fmaxf(pm, st[1][r]);
      pm = fmaxf(pm, __shfl_xor(pm, 32));

      // defer-max rescale (THR = 8 in log2 domain)
      if (__any(pm > m + 8.f)) {
        float mn = fmaxf(m, pm);
        float sf = exp2a(m - mn);
        m = mn;
        l *= sf;
#pragma unroll
        for (int mo = 0; mo < 2; ++mo)
#pragma unroll
          for (int r = 0; r < 16; ++r) acc[mo][r] *= sf;
      }

      // P = exp2(S - m), row sum
      float rs = 0.f;
#pragma unroll
      for (int mm = 0; mm < 2; ++mm)
#pragma unroll
        for (int r = 0; r < 16; ++r) {
          float p = exp2a(st[mm][r] - m);
          st[mm][r] = p;
          rs += p;
        }
      rs += __shfl_xor(rs, 32);
      l += rs;

      // P -> bf16 B-frags in-register (cvt_pk + permlane32_swap)
      bf16x8 pf[4];
#pragma unroll
      for (int mm = 0; mm < 2; ++mm)
#pragma unroll
        for (int g = 0; g < 2; ++g) {
          uint32_t a1 = cvtpk(st[mm][8 * g + 0], st[mm][8 * g + 1]);
          uint32_t a2 = cvtpk(st[mm][8 * g + 2], st[mm][8 * g + 3]);
          uint32_t b1 = cvtpk(st[mm][8 * g + 4], st[mm][8 * g + 5]);
          uint32_t b2 = cvtpk(st[mm][8 * g + 6], st[mm][8 * g + 7]);
          plswap(a1, b1);
          plswap(a2, b2);
          union { uint32_t w[4]; bf16x8 v; } u;
          u.w[0] = a1; u.w[1] = a2; u.w[2] = b1; u.w[3] = b2;
          pf[mm * 2 + g] = u.v;
        }

      // O^T += V^T @ P^T
#pragma unroll
      for (int ks = 0; ks < 4; ++ks) {
#pragma unroll
        for (int mo = 0; mo < 2; ++mo) {
          int row = mo * 32 + ql;
          int ch = (ks * 2 + hi) ^ (row & 7);
          bf16x8 vf = *(const bf16x8*)&SB[2 + cur][row * 64 + ch * 8];
          acc[mo] = __builtin_amdgcn_mfma_f32_32x32x16_bf16(vf, pf[ks], acc[mo], 0, 0, 0);
        }
      }
    }

    asm volatile("s_waitcnt vmcnt(0)" ::: "memory");  // next tile's stage landed
    __builtin_amdgcn_s_barrier();
  }
#undef STAGE

  // epilogue: O^T -> LDS (transpose, swizzled) -> coalesced global store
  __syncthreads();
  uint16_t* ost = &SB[0][0];  // 256 rows x 64 cols
  {
    float inv = 1.0f / l;
    uint16_t* wst = ost + wid * 2048;
#pragma unroll
    for (int mo = 0; mo < 2; ++mo)
#pragma unroll
      for (int r = 0; r < 16; r += 2) {
        int hd = mo * 32 + (r & 3) + 8 * (r >> 2) + 4 * hi;
        uint32_t pk = pack2(acc[mo][r] * inv, acc[mo][r + 1] * inv);
        int col = hd ^ ((ql & 7) << 3);
        *(uint32_t*)&wst[ql * 64 + col] = pk;
      }
  }
  __syncthreads();
  {
    int row = tid >> 1, half = tid & 1;
    int r7 = row & 7;
    int b = bh >> 4, h = bh & 15;
    size_t g = (size_t)(b * T_ + q0 + row) * D_ + h * 64 + half * 32;
#pragma unroll
    for (int j = 0; j < 4; ++j) {
      int cc = half * 4 + j;
      uint4 val = *(const uint4*)&ost[row * 64 + (cc ^ r7) * 8];
      *(uint4*)&O[g + j * 8] = val;
    }
  }
}

// ---------------- launcher ----------------
extern "C" void kernel_launch(void* const* d_in, const int* in_sizes, int n_in,
                              void* d_out, int out_size, void* d_ws, size_t ws_size,
                              hipStream_t stream) {
  (void)in_sizes; (void)n_in; (void)out_size; (void)ws_size;
  const float* q  = (const float*)d_in[0];
  const float* k  = (const float*)d_in[1];
  const float* v  = (const float*)d_in[2];
  // d_in[3] = mask (causal; structure hardcoded)
  const float* Wq = (const float*)d_in[4];
  const float* Wk = (const float*)d_in[5];
  const float* Wv = (const float*)d_in[6];
  const float* Wo = (const float*)d_in[7];

  uint8_t* ws = (uint8_t*)d_ws;
  const size_t MB = 1u << 20;
  uint16_t* WQB = (uint16_t*)(ws + 0 * MB);
  uint16_t* WKB = (uint16_t*)(ws + 2 * MB);
  uint16_t* WVB = (uint16_t*)(ws + 4 * MB);
  uint16_t* WOB = (uint16_t*)(ws + 6 * MB);
  uint16_t* XQ  = (uint16_t*)(ws + 8 * MB);
  uint16_t* XK  = (uint16_t*)(ws + 24 * MB);
  uint16_t* XV  = (uint16_t*)(ws + 40 * MB);
  uint16_t* QH  = (uint16_t*)(ws + 56 * MB);
  uint16_t* KH  = (uint16_t*)(ws + 72 * MB);
  uint16_t* VT  = (uint16_t*)(ws + 88 * MB);
  uint16_t* AC  = (uint16_t*)(ws + 8 * MB);  // alias XQ (dead after Q proj)

  const int nBig = B_ * T_ * D_;   // 8388608
  const int nW   = D_ * D_;        // 1048576
  cvt_bf16<<<nBig / 2048, 256, 0, stream>>>(q, XQ, nBig);
  cvt_bf16<<<nBig / 2048, 256, 0, stream>>>(k, XK, nBig);
  cvt_bf16<<<nBig / 2048, 256, 0, stream>>>(v, XV, nBig);
  cvt_bf16<<<nW / 2048, 256, 0, stream>>>(Wq, WQB, nW);
  cvt_bf16<<<nW / 2048, 256, 0, stream>>>(Wk, WKB, nW);
  cvt_bf16<<<nW / 2048, 256, 0, stream>>>(Wv, WVB, nW);
  cvt_bf16<<<nW / 2048, 256, 0, stream>>>(Wo, WOB, nW);

  dim3 ggrid(B_ * T_ / 128, D_ / 128);
  // Q scale = HD^-0.5 * log2(e) -> softmax in exp2 domain
  const float qscale = 0.125f * 1.44269504088896340736f;
  gemm_bt<0><<<ggrid, 256, 0, stream>>>(XQ, WQB, QH, D_, qscale);
  gemm_bt<1><<<ggrid, 256, 0, stream>>>(XK, WKB, KH, D_, 1.0f);
  gemm_bt<2><<<ggrid, 256, 0, stream>>>(XV, WVB, VT, D_, 1.0f);

  attn_fwd<<<dim3(T_ / 256 * 64), 512, 0, stream>>>(QH, KH, VT, AC);

  gemm_bt<3><<<ggrid, 256, 0, stream>>>(AC, WOB, d_out, D_, 1.0f);
}

// Round 4
// 175.728 us; speedup vs baseline: 2.0869x; 1.0605x over previous
//
#include <hip/hip_runtime.h>
#include <stdint.h>

#define B_  4
#define T_  2048
#define D_  1024
#define H_  16
#define HD_ 64
#define KK_ 1024

typedef __bf16 bf16_t;
typedef __bf16 bf16x8 __attribute__((ext_vector_type(8)));
typedef float  f32x4  __attribute__((ext_vector_type(4)));
typedef float  f32x16 __attribute__((ext_vector_type(16)));

__device__ __forceinline__ uint16_t f2bf(float f) {
  uint32_t x = __float_as_uint(f);
  uint32_t r = (x + 0x7fffu + ((x >> 16) & 1u)) >> 16;
  return (uint16_t)r;
}

__device__ __forceinline__ uint32_t pack2(float a, float b) {
  return (uint32_t)f2bf(a) | ((uint32_t)f2bf(b) << 16);
}

__device__ __forceinline__ float exp2a(float x) {
  float r;
  asm("v_exp_f32 %0, %1" : "=v"(r) : "v"(x));
  return r;
}

__device__ __forceinline__ uint32_t cvtpk(float a, float b) {
  uint32_t r;
  asm("v_cvt_pk_bf16_f32 %0, %1, %2" : "=v"(r) : "v"(a), "v"(b));
  return r;
}

__device__ __forceinline__ void plswap(uint32_t& a, uint32_t& b) {
  asm("v_permlane32_swap_b32 %0, %1" : "+v"(a), "+v"(b));
}

// async 16B global->LDS; lds dst is wave-uniform base (+lane*16 by HW)
__device__ __forceinline__ void gll16(const void* g, void* l) {
  __builtin_amdgcn_global_load_lds(
      (const __attribute__((address_space(1))) void*)g,
      (__attribute__((address_space(3))) void*)l, 16, 0, 0);
}

// ---------------- fp32 -> bf16 conversion (merged launches) ----------------
__global__ __launch_bounds__(256) void cvt3(const float* __restrict__ s0,
                                            const float* __restrict__ s1,
                                            const float* __restrict__ s2,
                                            uint16_t* __restrict__ d0,
                                            uint16_t* __restrict__ d1,
                                            uint16_t* __restrict__ d2) {
  const float* in = blockIdx.y == 0 ? s0 : (blockIdx.y == 1 ? s1 : s2);
  uint16_t* out = blockIdx.y == 0 ? d0 : (blockIdx.y == 1 ? d1 : d2);
  int i = (blockIdx.x * 256 + threadIdx.x) * 8;
  float4 a = *(const float4*)(in + i);
  float4 b = *(const float4*)(in + i + 4);
  uint4 u;
  u.x = pack2(a.x, a.y);
  u.y = pack2(a.z, a.w);
  u.z = pack2(b.x, b.y);
  u.w = pack2(b.z, b.w);
  *(uint4*)(out + i) = u;
}

__global__ __launch_bounds__(256) void cvtW(const float* __restrict__ s0,
                                            const float* __restrict__ s1,
                                            const float* __restrict__ s2,
                                            const float* __restrict__ s3,
                                            uint16_t* __restrict__ d0,
                                            uint16_t* __restrict__ d1,
                                            uint16_t* __restrict__ d2,
                                            uint16_t* __restrict__ d3) {
  const float* in = blockIdx.y == 0 ? s0 : (blockIdx.y == 1 ? s1 :
                    (blockIdx.y == 2 ? s2 : s3));
  uint16_t* out = blockIdx.y == 0 ? d0 : (blockIdx.y == 1 ? d1 :
                  (blockIdx.y == 2 ? d2 : d3));
  int i = (blockIdx.x * 256 + threadIdx.x) * 8;
  float4 a = *(const float4*)(in + i);
  float4 b = *(const float4*)(in + i + 4);
  uint4 u;
  u.x = pack2(a.x, a.y);
  u.y = pack2(a.z, a.w);
  u.z = pack2(b.x, b.y);
  u.w = pack2(b.z, b.w);
  *(uint4*)(out + i) = u;
}

// ---------------- deep-pipelined GEMM: C = A[M,K] @ W[N,K]^T ----------------
// BM=128, BN=256, BK=32, 8 waves (2M x 4N), 64x64 per wave.
// 4 LDS buffers, stage-3-ahead, counted vmcnt(6) (T3+T4), setprio (T5).
// mode 0: Q -> bf16 [B,H,T,64] scaled; 1: K -> same; 2: V -> bf16 [B,H,64,T];
// mode 3: O -> fp32 [M, D_].
__global__ __launch_bounds__(512, 2)
void gemm8(const uint16_t* __restrict__ a0, const uint16_t* __restrict__ a1,
           const uint16_t* __restrict__ a2, const uint16_t* __restrict__ w0,
           const uint16_t* __restrict__ w1, const uint16_t* __restrict__ w2,
           void* __restrict__ o0, void* __restrict__ o1, void* __restrict__ o2,
           int mode_base, float scale0) {
  __shared__ __align__(16) uint16_t Ab[4][128 * 32];  // 32 KB
  __shared__ __align__(16) uint16_t Bb[4][256 * 32];  // 64 KB

  const int nwg = gridDim.x;
  const int bid = blockIdx.x;
  const int cpx = nwg >> 3;                       // nwg % 8 == 0
  const int swz = (bid & 7) * cpx + (bid >> 3);   // XCD-contiguous chunks
  const int g = swz >> 8;                         // 256 blocks per gemm
  const int r = swz & 255;
  const int mt = r >> 2, nt = r & 3;
  const int m0 = mt * 128, n0 = nt * 256;

  const uint16_t* A = g == 0 ? a0 : (g == 1 ? a1 : a2);
  const uint16_t* W = g == 0 ? w0 : (g == 1 ? w1 : w2);
  void* Out = g == 0 ? o0 : (g == 1 ? o1 : o2);
  const int mode = mode_base + g;
  const float scale = (mode == 0) ? scale0 : 1.0f;

  const int tid = threadIdx.x;
  const int wid = tid >> 6, lane = tid & 63;
  const int fr = lane & 15, fq = lane >> 4;
  const int wm = wid >> 2, wn = wid & 3;

  f32x4 acc[4][4];
#pragma unroll
  for (int i = 0; i < 4; ++i)
#pragma unroll
    for (int j = 0; j < 4; ++j) acc[i][j] = (f32x4){0.f, 0.f, 0.f, 0.f};

  const int NT = KK_ / 32;  // 32 tiles

#define STAGE(bi, t)                                                          \
  do {                                                                        \
    {                                                                         \
      int row = wid * 16 + (lane >> 2);                                       \
      int ch = (lane & 3) ^ ((row >> 1) & 3);                                 \
      gll16(A + (size_t)(m0 + row) * KK_ + (t) * 32 + ch * 8,                 \
            &Ab[bi][wid * 512]);                                              \
    }                                                                         \
    _Pragma("unroll")                                                         \
    for (int c = 0; c < 2; ++c) {                                             \
      int row = c * 128 + wid * 16 + (lane >> 2);                             \
      int ch = (lane & 3) ^ ((row >> 1) & 3);                                 \
      gll16(W + (size_t)(n0 + row) * KK_ + (t) * 32 + ch * 8,                 \
            &Bb[bi][c * 4096 + wid * 512]);                                   \
    }                                                                         \
  } while (0)

  // prologue: stage tiles 0..2, wait for tile 0 (6 = tiles 1,2 still flying)
  STAGE(0, 0);
  STAGE(1, 1);
  STAGE(2, 2);
  asm volatile("s_waitcnt vmcnt(6)" ::: "memory");
  __builtin_amdgcn_s_barrier();

#pragma unroll 4
  for (int t = 0; t < NT; ++t) {
    const int cur = t & 3;
    bf16x8 af[4], bfr[4];
#pragma unroll
    for (int i = 0; i < 4; ++i) {
      int ra = wm * 64 + i * 16 + fr;
      af[i] = *(const bf16x8*)&Ab[cur][ra * 32 + ((fq ^ ((ra >> 1) & 3)) << 3)];
      int rb = wn * 64 + i * 16 + fr;
      bfr[i] = *(const bf16x8*)&Bb[cur][rb * 32 + ((fq ^ ((rb >> 1) & 3)) << 3)];
    }
    if (t + 3 < NT) STAGE((t + 3) & 3, t + 3);
    __builtin_amdgcn_s_setprio(1);
#pragma unroll
    for (int mf = 0; mf < 4; ++mf)
#pragma unroll
      for (int nf = 0; nf < 4; ++nf)
        acc[mf][nf] = __builtin_amdgcn_mfma_f32_16x16x32_bf16(af[mf], bfr[nf],
                                                              acc[mf][nf], 0, 0, 0);
    __builtin_amdgcn_s_setprio(0);
    if (t + 1 < NT) {
      if (t + 3 < NT) {
        asm volatile("s_waitcnt vmcnt(6)" ::: "memory");
      } else if (t + 2 < NT) {
        asm volatile("s_waitcnt vmcnt(3)" ::: "memory");
      } else {
        asm volatile("s_waitcnt vmcnt(0)" ::: "memory");
      }
      __builtin_amdgcn_s_barrier();
    }
  }
#undef STAGE

  // epilogue
#pragma unroll
  for (int mf = 0; mf < 4; ++mf) {
#pragma unroll
    for (int nf = 0; nf < 4; ++nf) {
      int m = m0 + wm * 64 + mf * 16 + fq * 4;
      int n = n0 + wn * 64 + nf * 16 + fr;
      if (mode == 2) {
        int b = m >> 11, t = m & (T_ - 1);
        int h = n >> 6, hd = n & 63;
        uint2 pk;
        pk.x = pack2(acc[mf][nf][0], acc[mf][nf][1]);
        pk.y = pack2(acc[mf][nf][2], acc[mf][nf][3]);
        uint16_t* dst = (uint16_t*)Out + ((((size_t)b * H_ + h) * HD_ + hd) * T_ + t);
        *(uint2*)dst = pk;
      } else if (mode == 3) {
#pragma unroll
        for (int rr = 0; rr < 4; ++rr)
          ((float*)Out)[(size_t)(m + rr) * D_ + n] = acc[mf][nf][rr];
      } else {
#pragma unroll
        for (int rr = 0; rr < 4; ++rr) {
          int mm = m + rr;
          int b = mm >> 11, t = mm & (T_ - 1);
          int h = n >> 6, hd = n & 63;
          ((uint16_t*)Out)[((((size_t)b * H_ + h) * T_ + t) << 6) + hd] =
              f2bf(acc[mf][nf][rr] * scale);
        }
      }
    }
  }
}

// ---------------- flash attention (causal), 8 waves x 32 q, 32x32 swapped ----------------
// Qh,Kh: [B,H,T,64] bf16 (Q pre-scaled by 0.125*log2e -> exp2 domain). Vt: [B,H,64,T] bf16.
// O: bf16 [B,T,D] (heads concatenated).
__global__ __launch_bounds__(512)
void attn_fwd(const uint16_t* __restrict__ Qh, const uint16_t* __restrict__ Kh,
              const uint16_t* __restrict__ Vt, uint16_t* __restrict__ O) {
  // SB[0..1] = K double buffer, SB[2..3] = V double buffer; epilogue reuses all 32KB
  __shared__ __align__(16) uint16_t SB[4][64 * 64];

  const int tid = threadIdx.x, wid = tid >> 6, lane = tid & 63;
  const int ql = lane & 31, hi = lane >> 5;
  const int bid = blockIdx.x;
  const int qb = (T_ / 256 - 1) - (bid >> 6);  // longest blocks first
  const int bh = bid & 63;
  const int q0 = qb * 256;
  const int wq0 = q0 + wid * 32;  // this wave's first q row
  const size_t hoff = (size_t)bh * T_ * HD_;
  const uint16_t* Qp = Qh + hoff;
  const uint16_t* Kp = Kh + hoff;
  const uint16_t* Vp = Vt + hoff;

  // Q fragments (B-operand): lane owns q-row (wq0+ql); k = hd = ks*16 + hi*8 + j
  bf16x8 qf[4];
  {
    const uint16_t* qrow = Qp + (size_t)(wq0 + ql) * 64 + hi * 8;
#pragma unroll
    for (int ks = 0; ks < 4; ++ks) qf[ks] = *(const bf16x8*)(qrow + ks * 16);
  }

  float m = -1e30f, l = 0.f;
  f32x16 acc[2];  // O^T: row = hd = mo*32 + (r&3)+8*(r>>2)+4*hi, col = q = ql
#pragma unroll
  for (int mo = 0; mo < 2; ++mo)
#pragma unroll
    for (int r = 0; r < 16; ++r) acc[mo][r] = 0.f;

  const int ntiles = 4 * qb + 4;

#define STAGE(buf, t)                                                        \
  do {                                                                       \
    int row = wid * 8 + (lane >> 3);                                         \
    int sw = ((lane & 7) ^ (row & 7)) << 3;                                  \
    gll16(Kp + (size_t)((t) * 64 + row) * 64 + sw, &SB[buf][wid * 512]);     \
    gll16(Vp + (size_t)row * T_ + (t) * 64 + sw, &SB[2 + (buf)][wid * 512]); \
  } while (0)

  STAGE(0, 0);
  asm volatile("s_waitcnt vmcnt(0)" ::: "memory");
  __builtin_amdgcn_s_barrier();

  for (int it = 0; it < ntiles; ++it) {
    const int cur = it & 1;
    if (it + 1 < ntiles) STAGE(cur ^ 1, it + 1);  // prefetch next tile

    if (it * 64 <= wq0 + 31) {  // wave active unless whole tile above diagonal
      // S^T = K @ Q : col = q (lane-local), rows = kv
      f32x16 st[2];
#pragma unroll
      for (int mm = 0; mm < 2; ++mm)
#pragma unroll
        for (int r = 0; r < 16; ++r) st[mm][r] = 0.f;
#pragma unroll
      for (int ks = 0; ks < 4; ++ks) {
#pragma unroll
        for (int mm = 0; mm < 2; ++mm) {
          int row = mm * 32 + ql;
          int ch = (ks * 2 + hi) ^ (row & 7);
          bf16x8 kf = *(const bf16x8*)&SB[cur][row * 64 + ch * 8];
          st[mm] = __builtin_amdgcn_mfma_f32_32x32x16_bf16(kf, qf[ks], st[mm], 0, 0, 0);
        }
      }

      // causal mask (diagonal-straddling tiles only)
      if (it * 64 + 63 > wq0) {
        int qg = wq0 + ql;
#pragma unroll
        for (int mm = 0; mm < 2; ++mm)
#pragma unroll
          for (int r = 0; r < 16; ++r) {
            int kv = it * 64 + mm * 32 + (r & 3) + 8 * (r >> 2) + 4 * hi;
            if (kv > qg) st[mm][r] = -1e30f;
          }
      }

      // row max: 32 in-lane + pair lane
      float pm = st[0][0];
#pragma unroll
      for (int r = 1; r < 16; ++r) pm = fmaxf(pm, st[0][r]);
#pragma unroll
      for (int r = 0; r < 16; ++r) pm = fmaxf(pm, st[1][r]);
      pm = fmaxf(pm, __shfl_xor(pm, 32));

      // defer-max rescale (THR = 8 in log2 domain)
      if (__any(pm > m + 8.f)) {
        float mn = fmaxf(m, pm);
        float sf = exp2a(m - mn);
        m = mn;
        l *= sf;
#pragma unroll
        for (int mo = 0; mo < 2; ++mo)
#pragma unroll
          for (int r = 0; r < 16; ++r) acc[mo][r] *= sf;
      }

      // P = exp2(S - m), row sum
      float rs = 0.f;
#pragma unroll
      for (int mm = 0; mm < 2; ++mm)
#pragma unroll
        for (int r = 0; r < 16; ++r) {
          float p = exp2a(st[mm][r] - m);
          st[mm][r] = p;
          rs += p;
        }
      rs += __shfl_xor(rs, 32);
      l += rs;

      // P -> bf16 B-frags in-register (cvt_pk + permlane32_swap)
      bf16x8 pf[4];
#pragma unroll
      for (int mm = 0; mm < 2; ++mm)
#pragma unroll
        for (int g = 0; g < 2; ++g) {
          uint32_t a1 = cvtpk(st[mm][8 * g + 0], st[mm][8 * g + 1]);
          uint32_t a2 = cvtpk(st[mm][8 * g + 2], st[mm][8 * g + 3]);
          uint32_t b1 = cvtpk(st[mm][8 * g + 4], st[mm][8 * g + 5]);
          uint32_t b2 = cvtpk(st[mm][8 * g + 6], st[mm][8 * g + 7]);
          plswap(a1, b1);
          plswap(a2, b2);
          union { uint32_t w[4]; bf16x8 v; } u;
          u.w[0] = a1; u.w[1] = a2; u.w[2] = b1; u.w[3] = b2;
          pf[mm * 2 + g] = u.v;
        }

      // O^T += V^T @ P^T
#pragma unroll
      for (int ks = 0; ks < 4; ++ks) {
#pragma unroll
        for (int mo = 0; mo < 2; ++mo) {
          int row = mo * 32 + ql;
          int ch = (ks * 2 + hi) ^ (row & 7);
          bf16x8 vf = *(const bf16x8*)&SB[2 + cur][row * 64 + ch * 8];
          acc[mo] = __builtin_amdgcn_mfma_f32_32x32x16_bf16(vf, pf[ks], acc[mo], 0, 0, 0);
        }
      }
    }

    asm volatile("s_waitcnt vmcnt(0)" ::: "memory");  // next tile's stage landed
    __builtin_amdgcn_s_barrier();
  }
#undef STAGE

  // epilogue: O^T -> LDS (transpose, swizzled) -> coalesced global store
  __syncthreads();
  uint16_t* ost = &SB[0][0];  // 256 rows x 64 cols
  {
    float inv = 1.0f / l;
    uint16_t* wst = ost + wid * 2048;
#pragma unroll
    for (int mo = 0; mo < 2; ++mo)
#pragma unroll
      for (int r = 0; r < 16; r += 2) {
        int hd = mo * 32 + (r & 3) + 8 * (r >> 2) + 4 * hi;
        uint32_t pk = pack2(acc[mo][r] * inv, acc[mo][r + 1] * inv);
        int col = hd ^ ((ql & 7) << 3);
        *(uint32_t*)&wst[ql * 64 + col] = pk;
      }
  }
  __syncthreads();
  {
    int row = tid >> 1, half = tid & 1;
    int r7 = row & 7;
    int b = bh >> 4, h = bh & 15;
    size_t g = (size_t)(b * T_ + q0 + row) * D_ + h * 64 + half * 32;
#pragma unroll
    for (int j = 0; j < 4; ++j) {
      int cc = half * 4 + j;
      uint4 val = *(const uint4*)&ost[row * 64 + (cc ^ r7) * 8];
      *(uint4*)&O[g + j * 8] = val;
    }
  }
}

// ---------------- launcher ----------------
extern "C" void kernel_launch(void* const* d_in, const int* in_sizes, int n_in,
                              void* d_out, int out_size, void* d_ws, size_t ws_size,
                              hipStream_t stream) {
  (void)in_sizes; (void)n_in; (void)out_size; (void)ws_size;
  const float* q  = (const float*)d_in[0];
  const float* k  = (const float*)d_in[1];
  const float* v  = (const float*)d_in[2];
  // d_in[3] = mask (causal; structure hardcoded)
  const float* Wq = (const float*)d_in[4];
  const float* Wk = (const float*)d_in[5];
  const float* Wv = (const float*)d_in[6];
  const float* Wo = (const float*)d_in[7];

  uint8_t* ws = (uint8_t*)d_ws;
  const size_t MB = 1u << 20;
  uint16_t* WQB = (uint16_t*)(ws + 0 * MB);
  uint16_t* WKB = (uint16_t*)(ws + 2 * MB);
  uint16_t* WVB = (uint16_t*)(ws + 4 * MB);
  uint16_t* WOB = (uint16_t*)(ws + 6 * MB);
  uint16_t* XQ  = (uint16_t*)(ws + 8 * MB);
  uint16_t* XK  = (uint16_t*)(ws + 24 * MB);
  uint16_t* XV  = (uint16_t*)(ws + 40 * MB);
  uint16_t* QH  = (uint16_t*)(ws + 56 * MB);
  uint16_t* KH  = (uint16_t*)(ws + 72 * MB);
  uint16_t* VT  = (uint16_t*)(ws + 88 * MB);
  uint16_t* AC  = (uint16_t*)(ws + 8 * MB);  // alias XQ (dead after QKV gemm)

  // fp32 -> bf16 (2 launches)
  cvt3<<<dim3(B_ * T_ * D_ / 2048, 3), 256, 0, stream>>>(q, k, v, XQ, XK, XV);
  cvtW<<<dim3(D_ * D_ / 2048, 4), 256, 0, stream>>>(Wq, Wk, Wv, Wo, WQB, WKB, WVB, WOB);

  // Q scale = HD^-0.5 * log2(e) -> softmax in exp2 domain
  const float qscale = 0.125f * 1.44269504088896340736f;

  // fused QKV projections: 3 x 256 blocks
  gemm8<<<dim3(768), 512, 0, stream>>>(XQ, XK, XV, WQB, WKB, WVB,
                                       QH, KH, VT, 0, qscale);

  attn_fwd<<<dim3(T_ / 256 * 64), 512, 0, stream>>>(QH, KH, VT, AC);

  // output projection: 256 blocks, fp32 out
  gemm8<<<dim3(256), 512, 0, stream>>>(AC, nullptr, nullptr, WOB, nullptr, nullptr,
                                       d_out, nullptr, nullptr, 3, 1.0f);
}

// Round 5
// 164.001 us; speedup vs baseline: 2.2362x; 1.0715x over previous
//
#include <hip/hip_runtime.h>
#include <stdint.h>

#define B_  4
#define T_  2048
#define D_  1024
#define H_  16
#define HD_ 64
#define KK_ 1024

typedef __bf16 bf16_t;
typedef __bf16 bf16x8 __attribute__((ext_vector_type(8)));
typedef float  f32x4  __attribute__((ext_vector_type(4)));
typedef float  f32x16 __attribute__((ext_vector_type(16)));

__device__ __forceinline__ uint16_t f2bf(float f) {
  uint32_t x = __float_as_uint(f);
  uint32_t r = (x + 0x7fffu + ((x >> 16) & 1u)) >> 16;
  return (uint16_t)r;
}

__device__ __forceinline__ uint32_t pack2(float a, float b) {
  return (uint32_t)f2bf(a) | ((uint32_t)f2bf(b) << 16);
}

__device__ __forceinline__ float exp2a(float x) {
  float r;
  asm("v_exp_f32 %0, %1" : "=v"(r) : "v"(x));
  return r;
}

__device__ __forceinline__ uint32_t cvtpk(float a, float b) {
  uint32_t r;
  asm("v_cvt_pk_bf16_f32 %0, %1, %2" : "=v"(r) : "v"(a), "v"(b));
  return r;
}

__device__ __forceinline__ void plswap(uint32_t& a, uint32_t& b) {
  asm("v_permlane32_swap_b32 %0, %1" : "+v"(a), "+v"(b));
}

// async 16B global->LDS; lds dst is wave-uniform base (+lane*16 by HW)
__device__ __forceinline__ void gll16(const void* g, void* l) {
  __builtin_amdgcn_global_load_lds(
      (const __attribute__((address_space(1))) void*)g,
      (__attribute__((address_space(3))) void*)l, 16, 0, 0);
}

// ---------------- fp32 -> bf16 conversion (merged launches) ----------------
__global__ __launch_bounds__(256) void cvt3(const float* __restrict__ s0,
                                            const float* __restrict__ s1,
                                            const float* __restrict__ s2,
                                            uint16_t* __restrict__ d0,
                                            uint16_t* __restrict__ d1,
                                            uint16_t* __restrict__ d2) {
  const float* in = blockIdx.y == 0 ? s0 : (blockIdx.y == 1 ? s1 : s2);
  uint16_t* out = blockIdx.y == 0 ? d0 : (blockIdx.y == 1 ? d1 : d2);
  int i = (blockIdx.x * 256 + threadIdx.x) * 8;
  float4 a = *(const float4*)(in + i);
  float4 b = *(const float4*)(in + i + 4);
  uint4 u;
  u.x = pack2(a.x, a.y);
  u.y = pack2(a.z, a.w);
  u.z = pack2(b.x, b.y);
  u.w = pack2(b.z, b.w);
  *(uint4*)(out + i) = u;
}

__global__ __launch_bounds__(256) void cvtW(const float* __restrict__ s0,
                                            const float* __restrict__ s1,
                                            const float* __restrict__ s2,
                                            const float* __restrict__ s3,
                                            uint16_t* __restrict__ d0,
                                            uint16_t* __restrict__ d1,
                                            uint16_t* __restrict__ d2,
                                            uint16_t* __restrict__ d3) {
  const float* in = blockIdx.y == 0 ? s0 : (blockIdx.y == 1 ? s1 :
                    (blockIdx.y == 2 ? s2 : s3));
  uint16_t* out = blockIdx.y == 0 ? d0 : (blockIdx.y == 1 ? d1 :
                  (blockIdx.y == 2 ? d2 : d3));
  int i = (blockIdx.x * 256 + threadIdx.x) * 8;
  float4 a = *(const float4*)(in + i);
  float4 b = *(const float4*)(in + i + 4);
  uint4 u;
  u.x = pack2(a.x, a.y);
  u.y = pack2(a.z, a.w);
  u.z = pack2(b.x, b.y);
  u.w = pack2(b.z, b.w);
  *(uint4*)(out + i) = u;
}

// ---------------- deep-pipelined GEMM: C = A[M,K] @ W[N,K]^T ----------------
// BM=128, BN=256, BK=64, 8 waves (2M x 4N), 64x64 per wave.
// 3 LDS buffers (144KB), stage-2-ahead, counted vmcnt(6) (T3+T4), setprio (T5).
// mode 0: Q -> bf16 [B,H,T,64] scaled; 1: K -> same; 2: V -> bf16 [B,H,64,T];
// mode 3: O -> fp32 [M, D_].
__global__ __launch_bounds__(512, 2)
void gemm8(const uint16_t* __restrict__ a0, const uint16_t* __restrict__ a1,
           const uint16_t* __restrict__ a2, const uint16_t* __restrict__ w0,
           const uint16_t* __restrict__ w1, const uint16_t* __restrict__ w2,
           void* __restrict__ o0, void* __restrict__ o1, void* __restrict__ o2,
           int mode_base, float scale0) {
  __shared__ __align__(16) uint16_t Ab[3][128 * 64];  // 48 KB
  __shared__ __align__(16) uint16_t Bb[3][256 * 64];  // 96 KB

  const int nwg = gridDim.x;
  const int bid = blockIdx.x;
  const int cpx = nwg >> 3;                       // nwg % 8 == 0
  const int swz = (bid & 7) * cpx + (bid >> 3);   // XCD-contiguous chunks
  const int g = swz >> 8;                         // 256 blocks per gemm
  const int r = swz & 255;
  const int mt = r >> 2, nt = r & 3;
  const int m0 = mt * 128, n0 = nt * 256;

  const uint16_t* A = g == 0 ? a0 : (g == 1 ? a1 : a2);
  const uint16_t* W = g == 0 ? w0 : (g == 1 ? w1 : w2);
  void* Out = g == 0 ? o0 : (g == 1 ? o1 : o2);
  const int mode = mode_base + g;
  const float scale = (mode == 0) ? scale0 : 1.0f;

  const int tid = threadIdx.x;
  const int wid = tid >> 6, lane = tid & 63;
  const int fr = lane & 15, fq = lane >> 4;
  const int wm = wid >> 2, wn = wid & 3;
  const int srow = lane >> 3, c8 = lane & 7;  // staging row-in-group / chunk

  f32x4 acc[4][4];
#pragma unroll
  for (int i = 0; i < 4; ++i)
#pragma unroll
    for (int j = 0; j < 4; ++j) acc[i][j] = (f32x4){0.f, 0.f, 0.f, 0.f};

  const int NT = KK_ / 64;  // 16 tiles

  // Rows are 64 elems (8 chunks of 8). LDS[row][j] = src[row][j ^ (row&7)].
#define STAGE(bi, t)                                                          \
  do {                                                                        \
    _Pragma("unroll")                                                         \
    for (int c = 0; c < 2; ++c) {                                             \
      int row = c * 64 + wid * 8 + srow;                                      \
      int sw = (c8 ^ (row & 7)) << 3;                                         \
      gll16(A + (size_t)(m0 + row) * KK_ + (t) * 64 + sw,                     \
            &Ab[bi][c * 4096 + wid * 512]);                                   \
    }                                                                         \
    _Pragma("unroll")                                                         \
    for (int c = 0; c < 4; ++c) {                                             \
      int row = c * 64 + wid * 8 + srow;                                      \
      int sw = (c8 ^ (row & 7)) << 3;                                         \
      gll16(W + (size_t)(n0 + row) * KK_ + (t) * 64 + sw,                     \
            &Bb[bi][c * 4096 + wid * 512]);                                   \
    }                                                                         \
  } while (0)

  // prologue: stage tiles 0,1; wait tile 0 (6 = tile 1's loads still flying)
  STAGE(0, 0);
  STAGE(1, 1);
  asm volatile("s_waitcnt vmcnt(6)" ::: "memory");
  __builtin_amdgcn_s_barrier();

  int cur = 0;
  for (int t = 0; t < NT; ++t) {
    const uint16_t* Ac = &Ab[cur][0];
    const uint16_t* Bc = &Bb[cur][0];
    // k-slice 0 frags
    bf16x8 af0[4], bf0[4];
#pragma unroll
    for (int i = 0; i < 4; ++i) {
      int ra = wm * 64 + i * 16 + fr;
      af0[i] = *(const bf16x8*)&Ac[ra * 64 + ((fq ^ (ra & 7)) << 3)];
      int rb = wn * 64 + i * 16 + fr;
      bf0[i] = *(const bf16x8*)&Bc[rb * 64 + ((fq ^ (rb & 7)) << 3)];
    }
    // prefetch tile t+2
    if (t + 2 < NT) {
      int nb = cur + 2; if (nb >= 3) nb -= 3;
      STAGE(nb, t + 2);
    }
    // k-slice 1 frags
    bf16x8 af1[4], bf1[4];
#pragma unroll
    for (int i = 0; i < 4; ++i) {
      int ra = wm * 64 + i * 16 + fr;
      af1[i] = *(const bf16x8*)&Ac[ra * 64 + (((4 + fq) ^ (ra & 7)) << 3)];
      int rb = wn * 64 + i * 16 + fr;
      bf1[i] = *(const bf16x8*)&Bc[rb * 64 + (((4 + fq) ^ (rb & 7)) << 3)];
    }
    __builtin_amdgcn_s_setprio(1);
#pragma unroll
    for (int mf = 0; mf < 4; ++mf)
#pragma unroll
      for (int nf = 0; nf < 4; ++nf)
        acc[mf][nf] = __builtin_amdgcn_mfma_f32_16x16x32_bf16(af0[mf], bf0[nf],
                                                              acc[mf][nf], 0, 0, 0);
#pragma unroll
    for (int mf = 0; mf < 4; ++mf)
#pragma unroll
      for (int nf = 0; nf < 4; ++nf)
        acc[mf][nf] = __builtin_amdgcn_mfma_f32_16x16x32_bf16(af1[mf], bf1[nf],
                                                              acc[mf][nf], 0, 0, 0);
    __builtin_amdgcn_s_setprio(0);
    if (t + 1 < NT) {
      if (t + 2 < NT) {
        asm volatile("s_waitcnt vmcnt(6)" ::: "memory");  // t+1 landed, t+2 flying
      } else {
        asm volatile("s_waitcnt vmcnt(0)" ::: "memory");  // tail
      }
      __builtin_amdgcn_s_barrier();
    }
    ++cur; if (cur == 3) cur = 0;
  }
#undef STAGE

  // epilogue
#pragma unroll
  for (int mf = 0; mf < 4; ++mf) {
#pragma unroll
    for (int nf = 0; nf < 4; ++nf) {
      int m = m0 + wm * 64 + mf * 16 + fq * 4;
      int n = n0 + wn * 64 + nf * 16 + fr;
      if (mode == 2) {
        int b = m >> 11, t = m & (T_ - 1);
        int h = n >> 6, hd = n & 63;
        uint2 pk;
        pk.x = pack2(acc[mf][nf][0], acc[mf][nf][1]);
        pk.y = pack2(acc[mf][nf][2], acc[mf][nf][3]);
        uint16_t* dst = (uint16_t*)Out + ((((size_t)b * H_ + h) * HD_ + hd) * T_ + t);
        *(uint2*)dst = pk;
      } else if (mode == 3) {
#pragma unroll
        for (int rr = 0; rr < 4; ++rr)
          ((float*)Out)[(size_t)(m + rr) * D_ + n] = acc[mf][nf][rr];
      } else {
#pragma unroll
        for (int rr = 0; rr < 4; ++rr) {
          int mm = m + rr;
          int b = mm >> 11, t = mm & (T_ - 1);
          int h = n >> 6, hd = n & 63;
          ((uint16_t*)Out)[((((size_t)b * H_ + h) * T_ + t) << 6) + hd] =
              f2bf(acc[mf][nf][rr] * scale);
        }
      }
    }
  }
}

// ---------------- flash attention (causal), 8 waves x 32 q, 32x32 swapped ----------------
// Qh,Kh: [B,H,T,64] bf16 (Q pre-scaled by 0.125*log2e -> exp2 domain). Vt: [B,H,64,T] bf16.
// O: bf16 [B,T,D] (heads concatenated).
__global__ __launch_bounds__(512)
void attn_fwd(const uint16_t* __restrict__ Qh, const uint16_t* __restrict__ Kh,
              const uint16_t* __restrict__ Vt, uint16_t* __restrict__ O) {
  // SB[0..2] = K triple buffer, SB[3..5] = V triple buffer (48 KB).
  // Epilogue reuses SB[0..3] as a 256x64 staging tile.
  __shared__ __align__(16) uint16_t SB[6][64 * 64];

  const int tid = threadIdx.x, wid = tid >> 6, lane = tid & 63;
  const int ql = lane & 31, hi = lane >> 5;
  const int bid = blockIdx.x;
  const int qb = (T_ / 256 - 1) - (bid >> 6);  // longest blocks first
  const int bh = bid & 63;
  const int q0 = qb * 256;
  const int wq0 = q0 + wid * 32;  // this wave's first q row
  const size_t hoff = (size_t)bh * T_ * HD_;
  const uint16_t* Qp = Qh + hoff;
  const uint16_t* Kp = Kh + hoff;
  const uint16_t* Vp = Vt + hoff;

  // Q fragments (B-operand): lane owns q-row (wq0+ql); k = hd = ks*16 + hi*8 + j
  bf16x8 qf[4];
  {
    const uint16_t* qrow = Qp + (size_t)(wq0 + ql) * 64 + hi * 8;
#pragma unroll
    for (int ks = 0; ks < 4; ++ks) qf[ks] = *(const bf16x8*)(qrow + ks * 16);
  }

  float m = -1e30f, l = 0.f;
  f32x16 acc[2];  // O^T: row = hd = mo*32 + (r&3)+8*(r>>2)+4*hi, col = q = ql
#pragma unroll
  for (int mo = 0; mo < 2; ++mo)
#pragma unroll
    for (int r = 0; r < 16; ++r) acc[mo][r] = 0.f;

  const int ntiles = 4 * qb + 4;

#define STAGE(buf, t)                                                        \
  do {                                                                       \
    int row = wid * 8 + (lane >> 3);                                         \
    int sw = ((lane & 7) ^ (row & 7)) << 3;                                  \
    gll16(Kp + (size_t)((t) * 64 + row) * 64 + sw, &SB[buf][wid * 512]);     \
    gll16(Vp + (size_t)row * T_ + (t) * 64 + sw, &SB[3 + (buf)][wid * 512]); \
  } while (0)

  STAGE(0, 0);
  if (ntiles > 1) STAGE(1, 1);
  asm volatile("s_waitcnt vmcnt(2)" ::: "memory");
  __builtin_amdgcn_s_barrier();

  int cur = 0;
  for (int it = 0; it < ntiles; ++it) {
    if (it + 2 < ntiles) {
      int nb = cur + 2; if (nb >= 3) nb -= 3;
      STAGE(nb, it + 2);
    }

    if (it * 64 <= wq0 + 31) {  // wave active unless whole tile above diagonal
      // S^T = K @ Q : col = q (lane-local), rows = kv
      f32x16 st[2];
#pragma unroll
      for (int mm = 0; mm < 2; ++mm)
#pragma unroll
        for (int r = 0; r < 16; ++r) st[mm][r] = 0.f;
#pragma unroll
      for (int ks = 0; ks < 4; ++ks) {
#pragma unroll
        for (int mm = 0; mm < 2; ++mm) {
          int row = mm * 32 + ql;
          int ch = (ks * 2 + hi) ^ (row & 7);
          bf16x8 kf = *(const bf16x8*)&SB[cur][row * 64 + ch * 8];
          st[mm] = __builtin_amdgcn_mfma_f32_32x32x16_bf16(kf, qf[ks], st[mm], 0, 0, 0);
        }
      }

      // causal mask (diagonal-straddling tiles only)
      if (it * 64 + 63 > wq0) {
        int qg = wq0 + ql;
#pragma unroll
        for (int mm = 0; mm < 2; ++mm)
#pragma unroll
          for (int r = 0; r < 16; ++r) {
            int kv = it * 64 + mm * 32 + (r & 3) + 8 * (r >> 2) + 4 * hi;
            if (kv > qg) st[mm][r] = -1e30f;
          }
      }

      // row max: 32 in-lane + pair lane
      float pm = st[0][0];
#pragma unroll
      for (int r = 1; r < 16; ++r) pm = fmaxf(pm, st[0][r]);
#pragma unroll
      for (int r = 0; r < 16; ++r) pm = fmaxf(pm, st[1][r]);
      pm = fmaxf(pm, __shfl_xor(pm, 32));

      // defer-max rescale (THR = 8 in log2 domain)
      if (__any(pm > m + 8.f)) {
        float mn = fmaxf(m, pm);
        float sf = exp2a(m - mn);
        m = mn;
        l *= sf;
#pragma unroll
        for (int mo = 0; mo < 2; ++mo)
#pragma unroll
          for (int r = 0; r < 16; ++r) acc[mo][r] *= sf;
      }

      // P = exp2(S - m), row sum
      float rs = 0.f;
#pragma unroll
      for (int mm = 0; mm < 2; ++mm)
#pragma unroll
        for (int r = 0; r < 16; ++r) {
          float p = exp2a(st[mm][r] - m);
          st[mm][r] = p;
          rs += p;
        }
      rs += __shfl_xor(rs, 32);
      l += rs;

      // P -> bf16 B-frags in-register (cvt_pk + permlane32_swap)
      bf16x8 pf[4];
#pragma unroll
      for (int mm = 0; mm < 2; ++mm)
#pragma unroll
        for (int g = 0; g < 2; ++g) {
          uint32_t a1 = cvtpk(st[mm][8 * g + 0], st[mm][8 * g + 1]);
          uint32_t a2 = cvtpk(st[mm][8 * g + 2], st[mm][8 * g + 3]);
          uint32_t b1 = cvtpk(st[mm][8 * g + 4], st[mm][8 * g + 5]);
          uint32_t b2 = cvtpk(st[mm][8 * g + 6], st[mm][8 * g + 7]);
          plswap(a1, b1);
          plswap(a2, b2);
          union { uint32_t w[4]; bf16x8 v; } u;
          u.w[0] = a1; u.w[1] = a2; u.w[2] = b1; u.w[3] = b2;
          pf[mm * 2 + g] = u.v;
        }

      // O^T += V^T @ P^T
#pragma unroll
      for (int ks = 0; ks < 4; ++ks) {
#pragma unroll
        for (int mo = 0; mo < 2; ++mo) {
          int row = mo * 32 + ql;
          int ch = (ks * 2 + hi) ^ (row & 7);
          bf16x8 vf = *(const bf16x8*)&SB[3 + cur][row * 64 + ch * 8];
          acc[mo] = __builtin_amdgcn_mfma_f32_32x32x16_bf16(vf, pf[ks], acc[mo], 0, 0, 0);
        }
      }
    }

    if (it + 1 < ntiles) {
      if (it + 2 < ntiles) {
        asm volatile("s_waitcnt vmcnt(2)" ::: "memory");  // it+1 landed, it+2 flying
      } else {
        asm volatile("s_waitcnt vmcnt(0)" ::: "memory");  // tail
      }
      __builtin_amdgcn_s_barrier();
    }
    ++cur; if (cur == 3) cur = 0;
  }
#undef STAGE

  // epilogue: O^T -> LDS (transpose, swizzled) -> coalesced global store
  __syncthreads();
  uint16_t* ost = &SB[0][0];  // 256 rows x 64 cols
  {
    float inv = 1.0f / l;
    uint16_t* wst = ost + wid * 2048;
#pragma unroll
    for (int mo = 0; mo < 2; ++mo)
#pragma unroll
      for (int r = 0; r < 16; r += 2) {
        int hd = mo * 32 + (r & 3) + 8 * (r >> 2) + 4 * hi;
        uint32_t pk = pack2(acc[mo][r] * inv, acc[mo][r + 1] * inv);
        int col = hd ^ ((ql & 7) << 3);
        *(uint32_t*)&wst[ql * 64 + col] = pk;
      }
  }
  __syncthreads();
  {
    int row = tid >> 1, half = tid & 1;
    int r7 = row & 7;
    int b = bh >> 4, h = bh & 15;
    size_t g = (size_t)(b * T_ + q0 + row) * D_ + h * 64 + half * 32;
#pragma unroll
    for (int j = 0; j < 4; ++j) {
      int cc = half * 4 + j;
      uint4 val = *(const uint4*)&ost[row * 64 + (cc ^ r7) * 8];
      *(uint4*)&O[g + j * 8] = val;
    }
  }
}

// ---------------- launcher ----------------
extern "C" void kernel_launch(void* const* d_in, const int* in_sizes, int n_in,
                              void* d_out, int out_size, void* d_ws, size_t ws_size,
                              hipStream_t stream) {
  (void)in_sizes; (void)n_in; (void)out_size; (void)ws_size;
  const float* q  = (const float*)d_in[0];
  const float* k  = (const float*)d_in[1];
  const float* v  = (const float*)d_in[2];
  // d_in[3] = mask (causal; structure hardcoded)
  const float* Wq = (const float*)d_in[4];
  const float* Wk = (const float*)d_in[5];
  const float* Wv = (const float*)d_in[6];
  const float* Wo = (const float*)d_in[7];

  uint8_t* ws = (uint8_t*)d_ws;
  const size_t MB = 1u << 20;
  uint16_t* WQB = (uint16_t*)(ws + 0 * MB);
  uint16_t* WKB = (uint16_t*)(ws + 2 * MB);
  uint16_t* WVB = (uint16_t*)(ws + 4 * MB);
  uint16_t* WOB = (uint16_t*)(ws + 6 * MB);
  uint16_t* XQ  = (uint16_t*)(ws + 8 * MB);
  uint16_t* XK  = (uint16_t*)(ws + 24 * MB);
  uint16_t* XV  = (uint16_t*)(ws + 40 * MB);
  uint16_t* QH  = (uint16_t*)(ws + 56 * MB);
  uint16_t* KH  = (uint16_t*)(ws + 72 * MB);
  uint16_t* VT  = (uint16_t*)(ws + 88 * MB);
  uint16_t* AC  = (uint16_t*)(ws + 8 * MB);  // alias XQ (dead after QKV gemm)

  // fp32 -> bf16 (2 launches)
  cvt3<<<dim3(B_ * T_ * D_ / 2048, 3), 256, 0, stream>>>(q, k, v, XQ, XK, XV);
  cvtW<<<dim3(D_ * D_ / 2048, 4), 256, 0, stream>>>(Wq, Wk, Wv, Wo, WQB, WKB, WVB, WOB);

  // Q scale = HD^-0.5 * log2(e) -> softmax in exp2 domain
  const float qscale = 0.125f * 1.44269504088896340736f;

  // fused QKV projections: 3 x 256 blocks
  gemm8<<<dim3(768), 512, 0, stream>>>(XQ, XK, XV, WQB, WKB, WVB,
                                       QH, KH, VT, 0, qscale);

  attn_fwd<<<dim3(T_ / 256 * 64), 512, 0, stream>>>(QH, KH, VT, AC);

  // output projection: 256 blocks, fp32 out
  gemm8<<<dim3(256), 512, 0, stream>>>(AC, nullptr, nullptr, WOB, nullptr, nullptr,
                                       d_out, nullptr, nullptr, 3, 1.0f);
}